// Round 3
// baseline (28.943 us; speedup 1.0000x reference)
//
#include <hip/hip_runtime.h>

// out[b,h,w,8*i+j] = x[b,h,w,i] * weight[h,w,j] + bias
// x: (32,112,112,8) f32, weight: (112,112,8) f32, bias: (1,) f32
// out: (32,112,112,64) f32
//
// Thread -> one output float4. Block (256 thr) = 16 pixels x 16 float4-subs.
// grid.x = 12544/16 = 784 pixel-groups, grid.y = 32 batches.
// hw/pix derived from block indices: no integer div/mod on the thread path.
// Output stores + x loads are nontemporal (streamed, no L2 pollution);
// weight (401 KB, reused 32x across batches) stays cached.
// NB: nontemporal builtins need a native vector type, not HIP float4 struct.

typedef float f32x4 __attribute__((ext_vector_type(4)));

#define HW_PIX (112 * 112)   // 12544 = 784 * 16
#define PIX_PER_BLK 16

__global__ __launch_bounds__(256) void mult_layer_kernel(
    const float* __restrict__ x,
    const float* __restrict__ weight,
    const float* __restrict__ bias,
    float* __restrict__ out) {
  const int tid = threadIdx.x;
  const int p   = tid >> 4;          // pixel within block (0..15)
  const int sub = tid & 15;          // float4 index within 64 channels
  const int i   = sub >> 1;          // x channel (0..7)
  const int j0  = (sub & 1) << 2;    // weight channel base (0 or 4)

  const int hw  = blockIdx.x * PIX_PER_BLK + p;   // 0..12543, exact
  const int pix = blockIdx.y * HW_PIX + hw;       // b*HW + hw

  const float xv = __builtin_nontemporal_load(x + pix * 8 + i);
  const f32x4 wv = *reinterpret_cast<const f32x4*>(weight + hw * 8 + j0);
  const float bv = bias[0];

  f32x4 o;
  o.x = fmaf(xv, wv.x, bv);
  o.y = fmaf(xv, wv.y, bv);
  o.z = fmaf(xv, wv.z, bv);
  o.w = fmaf(xv, wv.w, bv);

  f32x4* dst = reinterpret_cast<f32x4*>(out) + ((long)pix * 16 + sub);
  __builtin_nontemporal_store(o, dst);
}

extern "C" void kernel_launch(void* const* d_in, const int* in_sizes, int n_in,
                              void* d_out, int out_size, void* d_ws, size_t ws_size,
                              hipStream_t stream) {
  const float* x      = (const float*)d_in[0];
  const float* weight = (const float*)d_in[1];
  const float* bias   = (const float*)d_in[2];
  float* out          = (float*)d_out;

  dim3 grid(HW_PIX / PIX_PER_BLK, 32, 1);   // (784, 32)
  dim3 block(256, 1, 1);
  mult_layer_kernel<<<grid, block, 0, stream>>>(x, weight, bias, out);
}

// Round 4
// 22.907 us; speedup vs baseline: 1.2635x; 1.2635x over previous
//
#include <hip/hip_runtime.h>

// out[b,h,w,8*i+j] = x[b,h,w,i] * weight[h,w,j] + bias
// x: (32,112,112,8) f32, weight: (112,112,8) f32, bias: (1,) f32
// out: (32,112,112,64) f32
//
// Thread -> one output float4 per batch, looped over 4 batches.
// Block (256 thr) = 16 pixels x 16 float4-subs; grid = (784 pixel-groups, 8 batch-groups).
// weight float4 loaded ONCE per thread, reused for 4 batches (in-register).
// All loads/stores plain (R3 showed nontemporal hints regress -15% on gfx950).

typedef float f32x4 __attribute__((ext_vector_type(4)));

#define HW_PIX (112 * 112)   // 12544 = 784 * 16
#define PIX_PER_BLK 16
#define B_PER_THREAD 4

__global__ __launch_bounds__(256) void mult_layer_kernel(
    const float* __restrict__ x,
    const float* __restrict__ weight,
    const float* __restrict__ bias,
    float* __restrict__ out) {
  const int tid = threadIdx.x;
  const int p   = tid >> 4;          // pixel within block (0..15)
  const int sub = tid & 15;          // float4 index within 64 channels
  const int i   = sub >> 1;          // x channel (0..7)
  const int j0  = (sub & 1) << 2;    // weight channel base (0 or 4)

  const int hw = blockIdx.x * PIX_PER_BLK + p;        // 0..12543
  const int b0 = blockIdx.y * B_PER_THREAD;           // 0,4,...,28

  const f32x4 wv = *reinterpret_cast<const f32x4*>(weight + hw * 8 + j0);
  const float bv = bias[0];

  const float* xp = x + ((long)b0 * HW_PIX + hw) * 8 + i;
  f32x4* op = reinterpret_cast<f32x4*>(out) + ((long)b0 * HW_PIX + hw) * 16 + sub;

  // Issue all 4 x loads first (independent), then compute + store.
  float xv[B_PER_THREAD];
#pragma unroll
  for (int bb = 0; bb < B_PER_THREAD; ++bb)
    xv[bb] = xp[(long)bb * HW_PIX * 8];

#pragma unroll
  for (int bb = 0; bb < B_PER_THREAD; ++bb) {
    f32x4 o;
    o.x = fmaf(xv[bb], wv.x, bv);
    o.y = fmaf(xv[bb], wv.y, bv);
    o.z = fmaf(xv[bb], wv.z, bv);
    o.w = fmaf(xv[bb], wv.w, bv);
    op[(long)bb * HW_PIX * 16] = o;
  }
}

extern "C" void kernel_launch(void* const* d_in, const int* in_sizes, int n_in,
                              void* d_out, int out_size, void* d_ws, size_t ws_size,
                              hipStream_t stream) {
  const float* x      = (const float*)d_in[0];
  const float* weight = (const float*)d_in[1];
  const float* bias   = (const float*)d_in[2];
  float* out          = (float*)d_out;

  dim3 grid(HW_PIX / PIX_PER_BLK, 32 / B_PER_THREAD, 1);   // (784, 8)
  dim3 block(256, 1, 1);
  mult_layer_kernel<<<grid, block, 0, stream>>>(x, weight, bias, out);
}